// Round 8
// baseline (261.364 us; speedup 1.0000x reference)
//
#include <hip/hip_runtime.h>
#include <hip/hip_bf16.h>

typedef unsigned short bf16_t;  // raw bf16 bits
typedef __attribute__((ext_vector_type(4))) float f32x4;
typedef __attribute__((ext_vector_type(8))) unsigned short us8;

#define CAP 64  // fixed bucket capacity per dst row (Poisson(12): P(deg>=64)~1e-25)

__device__ __forceinline__ float bf2f(bf16_t u) {
  return __uint_as_float(((unsigned int)u) << 16);
}
__device__ __forceinline__ bf16_t f2bf(float f) {
  unsigned int u = __float_as_uint(f);
  return (bf16_t)((u + 0x7FFFu + ((u >> 16) & 1u)) >> 16);  // RNE
}
// accumulate 2 bf16 (packed in dword d) into float2 (elem0=low, elem1=high)
__device__ __forceinline__ void acc2(float2& a, unsigned int d) {
  a.x += __uint_as_float(d << 16);
  a.y += __uint_as_float(d & 0xffff0000u);
}

// Identifier kernel, zero-parameter form (load-bearing: parameterized variant
// broke the harness in rounds 1-5).
__global__ void UnifiedGNN_56521769616171_kernel() {}

// ---------------- setup ----------------
// Fixed-capacity bucket "CSR": row d owns csr[d*CAP .. d*CAP+63]. One atomic
// pass (gnn_fill) produces BOTH the degree (cnt) and slot positions.
// Buckets are NOT prefilled: the aggregation clamps the INDEX per batch
// (v_cndmask: slot >= cnt -> zero-row N) -- branch-free, exact +0.0 dummies,
// bit-identical to the prefilled variant, and no 12.8MB prefill traffic.
// dis never materialized: consumers compute rsqrtf(cnt[row]+1) on the fly.

// zero cnt; zero A row N; build transposed+swizzled bf16 copies of W1/W2 in
// global (Wt layout: us8 chunk index c*16 + (kb ^ (c&15))) so GEMM staging is
// a linear 32 KB copy.
__global__ void gnn_zero(int* cnt, int n, bf16_t* Azrow,
                         const float* W1, const float* W2,
                         bf16_t* Wt1g, bf16_t* Wt2g) {
  int gid = blockIdx.x * 256 + threadIdx.x;
  if (blockIdx.x == 0 && threadIdx.x < 64)
    ((unsigned int*)Azrow)[threadIdx.x] = 0u;
  if (gid < 4096) {
    const float* W = (gid < 2048) ? W1 : W2;
    bf16_t* dst = (gid < 2048) ? Wt1g : Wt2g;
    int j = gid & 2047;
    int c = j & 127;
    int kb = j >> 7;  // 0..15
    int k0 = kb << 3;
    us8 v;
#pragma unroll
    for (int q = 0; q < 8; q++) v[q] = f2bf(W[(size_t)(k0 + q) * 128 + c]);
    ((us8*)dst)[c * 16 + (kb ^ (c & 15))] = v;
  }
  if (gid < n) cnt[gid] = 0;
}

// single atomic pass: degree count AND slot placement. 2 edges/thread (int2
// loads); csr scatter via nontemporal store -- the 4B random write otherwise
// write-allocates a 64B line (R6 counters: 37MB WRITE_SIZE for 2.4MB payload,
// fill bound on allocate fetches, 0.5% VALU).
__global__ void gnn_fill(const int* src, const int* dst, int* cnt,
                         int* csr, int e, int n) {
  int i = blockIdx.x * 256 + threadIdx.x;
  int i0 = i * 2;
  if (i0 + 1 < e) {
    int2 d2 = *(const int2*)(dst + i0);
    int2 s2 = *(const int2*)(src + i0);
    if (d2.x >= 0 && d2.x < n) {
      int pos = atomicAdd(&cnt[d2.x], 1);
      if (pos < CAP)
        __builtin_nontemporal_store(s2.x, &csr[(size_t)d2.x * CAP + pos]);
    }
    if (d2.y >= 0 && d2.y < n) {
      int pos = atomicAdd(&cnt[d2.y], 1);
      if (pos < CAP)
        __builtin_nontemporal_store(s2.y, &csr[(size_t)d2.y * CAP + pos]);
    }
  } else if (i0 < e) {
    int d = dst[i0];
    if (d >= 0 && d < n) {
      int pos = atomicAdd(&cnt[d], 1);
      if (pos < CAP)
        __builtin_nontemporal_store(src[i0], &csr[(size_t)d * CAP + pos]);
    }
  }
}

// ------- MFMA GEMM: A[r][c] = dis[r] * sum_k X[r][k] * W[k][c] -> bf16 -------
// Wg is PRE-TRANSPOSED+SWIZZLED bf16 (built in gnn_zero): staging is a pure
// linear 32 KB us8 copy. 512 threads = 8 waves x 16 rows = 128 rows/block.
// Swizzle: Wt[c][k] with 16B chunk kb ^= c&15 -> B-frag ds_read_b128
// bank-uniform. Per wave: 16 rows x 128 cols, 8 acc f32x4, 4 k-steps of
// mfma 16x16x32 bf16. C/D layout (m89): col=lane&15, row=(lane>>4)*4+reg.
// xfmt=0: X f32, in-register hi/lo split (2 MFMAs/k-step, f32-fidelity X).
// xfmt=1: X bf16 (1 MFMA/k-step). dis computed on the fly from cnt.
// s_nop 2 covers VALU->MFMA SrcC hazard; epilogue s_nop 7 pair operand-tied.
__global__ __launch_bounds__(512) void gnn_gemm(const void* Xv,
    const bf16_t* Wg, const int* cnt, bf16_t* A, int n, int xfmt) {
  __shared__ __align__(16) bf16_t Wt[128 * 128];  // 32 KB
  int tid = threadIdx.x;

  // stage W: linear coalesced copy (already transposed+swizzled)
  for (int j = tid; j < 2048; j += 512)
    ((us8*)Wt)[j] = ((const us8*)Wg)[j];
  __syncthreads();

  int lane = tid & 63;
  int wid = tid >> 6;   // 0..7 (wave id)
  int l15 = lane & 15;
  int lk = lane >> 4;   // 0..3 (k-group)
  const bf16_t* Xb = (const bf16_t*)Xv;
  const float* Xf = (const float*)Xv;

  int rowbase = blockIdx.x * 128 + wid * 16;
  int arow = rowbase + l15;
  int arc = arow < n ? arow : (n - 1);  // clamp: garbage rows are never stored

  f32x4 acc[8];
#pragma unroll
  for (int c = 0; c < 8; c++) {
    acc[c][0] = 0.0f; acc[c][1] = 0.0f; acc[c][2] = 0.0f; acc[c][3] = 0.0f;
  }

#pragma unroll
  for (int ks = 0; ks < 4; ks++) {
    int kb = ks * 4 + lk;  // 16B chunk index in k
    us8 ah, al;
    if (xfmt == 0) {
      float4 a0 = *(const float4*)(Xf + (size_t)arc * 128 + kb * 8);
      float4 a1 = *(const float4*)(Xf + (size_t)arc * 128 + kb * 8 + 4);
      ah[0] = f2bf(a0.x); al[0] = f2bf(a0.x - bf2f(ah[0]));
      ah[1] = f2bf(a0.y); al[1] = f2bf(a0.y - bf2f(ah[1]));
      ah[2] = f2bf(a0.z); al[2] = f2bf(a0.z - bf2f(ah[2]));
      ah[3] = f2bf(a0.w); al[3] = f2bf(a0.w - bf2f(ah[3]));
      ah[4] = f2bf(a1.x); al[4] = f2bf(a1.x - bf2f(ah[4]));
      ah[5] = f2bf(a1.y); al[5] = f2bf(a1.y - bf2f(ah[5]));
      ah[6] = f2bf(a1.z); al[6] = f2bf(a1.z - bf2f(ah[6]));
      ah[7] = f2bf(a1.w); al[7] = f2bf(a1.w - bf2f(ah[7]));
    } else {
      ah = *(const us8*)(Xb + (size_t)arc * 128 + kb * 8);
    }
#pragma unroll
    for (int c = 0; c < 8; c++) {
      int col = c * 16 + l15;
      us8 bf = *(const us8*)&Wt[col * 128 + ((kb ^ l15) << 3)];
      asm volatile("s_nop 2\n\tv_mfma_f32_16x16x32_bf16 %0, %1, %2, %0"
                   : "+v"(acc[c]) : "v"(ah), "v"(bf));
    }
    if (xfmt == 0) {
#pragma unroll
      for (int c = 0; c < 8; c++) {
        int col = c * 16 + l15;
        us8 bf = *(const us8*)&Wt[col * 128 + ((kb ^ l15) << 3)];
        asm volatile("s_nop 2\n\tv_mfma_f32_16x16x32_bf16 %0, %1, %2, %0"
                     : "+v"(acc[c]) : "v"(al), "v"(bf));
      }
    }
  }
  // MFMA->VALU read hazard drain; operand-tied so acc reads can't hoist.
  asm volatile("s_nop 7\n\ts_nop 7"
               : "+v"(acc[0]), "+v"(acc[1]), "+v"(acc[2]), "+v"(acc[3]),
                 "+v"(acc[4]), "+v"(acc[5]), "+v"(acc[6]), "+v"(acc[7]));

#pragma unroll
  for (int j = 0; j < 4; j++) {
    int row = rowbase + lk * 4 + j;
    if (row < n) {
      float dd = rsqrtf((float)cnt[row] + 1.0f);
#pragma unroll
      for (int c = 0; c < 8; c++) {
        A[(size_t)row * 128 + c * 16 + l15] = f2bf(acc[c][j] * dd);
      }
    }
  }
}

// --- fused aggregation (+ optional residual+LN+relu) ---
// A holds dis[s]*h[s] (bf16), plus an all-zero row N. Bucket "CSR": row rc's
// srcs at csr[rc*CAP .. rc*CAP+cnt-1]; slots >= cnt are UNINITIALIZED --
// the raw index is replaced by the zero-row index N via a per-batch
// cndmask (e+l16 < c), keeping the gather loop branch-free with exact +0.0
// dummies and bit-identical accumulation order.
// 16 lanes per row (uint4 = 16B per lane), 4 rows per wave, 16 rows/block.
// 8-deep gather sub-batches, no launch-bounds cap (R3's cap -> spills).
// At structural L2/L3 random-gather ceiling (R2/R3/R4 triple-null) -- frozen.
__global__ void gnn_aggln(const bf16_t* A,
    const int* cnt, const int* csr, const float* bias,
    const float* ori, const float* lnw, const float* lnb,
    bf16_t* Bout, float* Fout, int n, int do_ln) {
  int wid = threadIdx.x >> 6;
  int lane = threadIdx.x & 63;
  int g = lane >> 4;    // group 0..3 within wave
  int l16 = lane & 15;  // lane within group
  int row = blockIdx.x * 16 + wid * 4 + g;
  bool active = row < n;
  int rc = active ? row : (n - 1);
  int c = cnt[rc];
  int pc = (c + 15) & ~15;
  if (pc > CAP) pc = CAP;
  const int* crow = csr + (size_t)rc * CAP;
  const uint4* Av4 = (const uint4*)A;

  float2 ac[4];
#pragma unroll
  for (int i = 0; i < 4; i++) ac[i] = make_float2(0.0f, 0.0f);

  for (int e = 0; e < pc; e += 16) {
    int raw = crow[e + l16];
    int sv = (e + l16 < c) ? raw : n;  // index clamp: dummy -> zero row N
#pragma unroll
    for (int half = 0; half < 2; half++) {
      uint4 va[8];
#pragma unroll
      for (int j = 0; j < 8; j++) {
        int s = __shfl(sv, (g << 4) + half * 8 + j);
        va[j] = Av4[(size_t)s * 16 + l16];
      }
#pragma unroll
      for (int j = 0; j < 8; j++) {
        acc2(ac[0], va[j].x);
        acc2(ac[1], va[j].y);
        acc2(ac[2], va[j].z);
        acc2(ac[3], va[j].w);
      }
    }
  }
  // self-loop term
  {
    uint4 sv4 = Av4[(size_t)rc * 16 + l16];
    acc2(ac[0], sv4.x);
    acc2(ac[1], sv4.y);
    acc2(ac[2], sv4.z);
    acc2(ac[3], sv4.w);
  }

  float dd = rsqrtf((float)c + 1.0f);
  float4 bb0 = *(const float4*)(bias + l16 * 8);
  float4 bb1 = *(const float4*)(bias + l16 * 8 + 4);
  float h[8];
  h[0] = dd * ac[0].x + bb0.x; h[1] = dd * ac[0].y + bb0.y;
  h[2] = dd * ac[1].x + bb0.z; h[3] = dd * ac[1].y + bb0.w;
  h[4] = dd * ac[2].x + bb1.x; h[5] = dd * ac[2].y + bb1.y;
  h[6] = dd * ac[3].x + bb1.z; h[7] = dd * ac[3].y + bb1.w;

  if (do_ln) {
    float4 o0 = *(const float4*)(ori + (size_t)rc * 128 + l16 * 8);
    float4 o1 = *(const float4*)(ori + (size_t)rc * 128 + l16 * 8 + 4);
    float v[8];
    v[0] = h[0] + o0.x; v[1] = h[1] + o0.y; v[2] = h[2] + o0.z; v[3] = h[3] + o0.w;
    v[4] = h[4] + o1.x; v[5] = h[5] + o1.y; v[6] = h[6] + o1.z; v[7] = h[7] + o1.w;
    float s = 0.0f, sq = 0.0f;
#pragma unroll
    for (int i = 0; i < 8; i++) { s += v[i]; sq += v[i] * v[i]; }
    for (int off = 8; off >= 1; off >>= 1) {  // intra-group (16-lane) reduce
      s += __shfl_xor(s, off);
      sq += __shfl_xor(sq, off);
    }
    float mu = s * (1.0f / 128.0f);
    float var = sq * (1.0f / 128.0f) - mu * mu;
    float inv = rsqrtf(var + 1e-5f);
    float4 w0 = *(const float4*)(lnw + l16 * 8);
    float4 w1 = *(const float4*)(lnw + l16 * 8 + 4);
    float4 c0 = *(const float4*)(lnb + l16 * 8);
    float4 c1 = *(const float4*)(lnb + l16 * 8 + 4);
    float wv[8] = {w0.x, w0.y, w0.z, w0.w, w1.x, w1.y, w1.z, w1.w};
    float cv[8] = {c0.x, c0.y, c0.z, c0.w, c1.x, c1.y, c1.z, c1.w};
    us8 o8;
#pragma unroll
    for (int i = 0; i < 8; i++) {
      float y = (v[i] - mu) * inv * wv[i] + cv[i];
      if (y < 0.0f) y = 0.0f;
      o8[i] = f2bf(y);
    }
    if (active) *(us8*)(Bout + (size_t)rc * 128 + l16 * 8) = o8;
  } else {
    if (active) {
      float4 f0 = make_float4(h[0], h[1], h[2], h[3]);
      float4 f1 = make_float4(h[4], h[5], h[6], h[7]);
      *(float4*)(Fout + (size_t)rc * 128 + l16 * 8) = f0;
      *(float4*)(Fout + (size_t)rc * 128 + l16 * 8 + 4) = f1;
    }
  }
}

// ---------------- driver ----------------

extern "C" void kernel_launch(void* const* d_in, const int* in_sizes, int n_in,
                              void* d_out, int out_size, void* d_ws, size_t ws_size,
                              hipStream_t stream) {
  UnifiedGNN_56521769616171_kernel<<<1, 64, 0, stream>>>();

  // input classification by size (identity under documented dict order)
  int nI = (n_in > 0 && n_in <= 16) ? n_in : 11;
  long best = -1;
  int iFeat = 0;
  for (int i = 0; i < nI; i++)
    if ((long)in_sizes[i] > best) { best = in_sizes[i]; iFeat = i; }
  int iW[2], iV[6], iE[2];
  int nW = 0, nV = 0, nE = 0;
  for (int i = 0; i < nI; i++) {
    if (i == iFeat) continue;
    int s = in_sizes[i];
    if (s == 128 * 128) { if (nW < 2) iW[nW++] = i; }
    else if (s == 128)  { if (nV < 6) iV[nV++] = i; }
    else                { if (nE < 2) iE[nE++] = i; }
  }
  int aFeat = 0, aEs = 1, aEd = 2, aW1 = 3, aB1 = 4, aW2 = 5, aB2 = 6,
      aL1w = 7, aL1b = 8, aL2w = 9, aL2b = 10;
  if (nW == 2 && nV == 6 && nE == 2) {
    aFeat = iFeat;
    aEs = iE[0]; aEd = iE[1];
    aW1 = iW[0]; aW2 = iW[1];
    aB1 = iV[0]; aB2 = iV[1];
    aL1w = iV[2]; aL1b = iV[3]; aL2w = iV[4]; aL2b = iV[5];
  }

  int N = 50000;
  int E = 600000;
  if (in_sizes[aFeat] > 0 && (in_sizes[aFeat] % 128) == 0) N = in_sizes[aFeat] / 128;
  if (in_sizes[aEs] > 0) E = in_sizes[aEs];

  const float* in_feat = (const float*)d_in[aFeat];
  const int*   esrc    = (const int*)d_in[aEs];
  const int*   edst    = (const int*)d_in[aEd];
  const float* W1      = (const float*)d_in[aW1];
  const float* b1      = (const float*)d_in[aB1];
  const float* W2      = (const float*)d_in[aW2];
  const float* b2      = (const float*)d_in[aB2];
  const float* ln1w    = (const float*)d_in[aL1w];
  const float* ln1b    = (const float*)d_in[aL1b];
  const float* ln2w    = (const float*)d_in[aL2w];
  const float* ln2b    = (const float*)d_in[aL2b];

  // workspace carve (~39 MB; ws_size = 256 MiB, confirmed by harness poison
  // fills: WRITE_SIZE=262144 KB per fillBufferAligned dispatch)
  char* base = (char*)d_ws;
  size_t off = 0;
  int* cnt = (int*)(base + off);      off += ((size_t)N * 4 + 255) & ~(size_t)255;
  int* csr = (int*)(base + off);      off += ((size_t)N * CAP * 4 + 255) & ~(size_t)255;
  bf16_t* A = (bf16_t*)(base + off);  off += ((size_t)(N + 1) * 256 + 255) & ~(size_t)255;  // +1 zero row
  bf16_t* B = (bf16_t*)(base + off);  off += ((size_t)N * 256 + 255) & ~(size_t)255;        // LN out
  bf16_t* Wt1g = (bf16_t*)(base + off); off += 32768;  // pre-swizzled bf16 W1
  bf16_t* Wt2g = (bf16_t*)(base + off); off += 32768;  // pre-swizzled bf16 W2

  int gZ = (N + 255) / 256;           // covers cnt zero + W convert (N >= 4096)
  int gE2 = ((E + 1) / 2 + 255) / 256;  // fill: 2 edges/thread
  int nt128 = (N + 127) / 128;
  int agg_grid = (N + 15) / 16;

  gnn_zero<<<gZ, 256, 0, stream>>>(cnt, N, A + (size_t)N * 128, W1, W2,
                                   Wt1g, Wt2g);
  gnn_fill<<<gE2, 256, 0, stream>>>(esrc, edst, cnt, csr, E, N);

  // conv1 + LN1(+res,relu):  A = dis*(in_feat@W1);  B = relu(LN1(agg(A)+b1 + ori))
  // conv1 GEMM consumes f32 X directly (in-register hi/lo split, xfmt=0)
  gnn_gemm<<<nt128, 512, 0, stream>>>(in_feat, Wt1g, cnt, A, N, 0);
  gnn_aggln<<<agg_grid, 256, 0, stream>>>(A, cnt, csr, b1, in_feat,
                                          ln1w, ln1b, B, (float*)nullptr, N, 1);

  // conv2 + LN2(+res,relu)
  gnn_gemm<<<nt128, 512, 0, stream>>>(B, Wt2g, cnt, A, N, 1);
  gnn_aggln<<<agg_grid, 256, 0, stream>>>(A, cnt, csr, b2, in_feat,
                                          ln2w, ln2b, B, (float*)nullptr, N, 1);

  // conv3 -> final f32 output
  gnn_gemm<<<nt128, 512, 0, stream>>>(B, Wt2g, cnt, A, N, 1);
  gnn_aggln<<<agg_grid, 256, 0, stream>>>(A, cnt, csr, b2,
                                          (const float*)nullptr, (const float*)nullptr,
                                          (const float*)nullptr, (bf16_t*)nullptr,
                                          (float*)d_out, N, 0);
}

// Round 9
// 248.362 us; speedup vs baseline: 1.0523x; 1.0523x over previous
//
#include <hip/hip_runtime.h>
#include <hip/hip_bf16.h>

typedef unsigned short bf16_t;  // raw bf16 bits
typedef __attribute__((ext_vector_type(4))) float f32x4;
typedef __attribute__((ext_vector_type(8))) unsigned short us8;

#define CAP 64  // fixed bucket capacity per dst row (Poisson(12): P(deg>=64)~1e-25)

__device__ __forceinline__ float bf2f(bf16_t u) {
  return __uint_as_float(((unsigned int)u) << 16);
}
__device__ __forceinline__ bf16_t f2bf(float f) {
  unsigned int u = __float_as_uint(f);
  return (bf16_t)((u + 0x7FFFu + ((u >> 16) & 1u)) >> 16);  // RNE
}
// accumulate 2 bf16 (packed in dword d) into float2 (elem0=low, elem1=high)
__device__ __forceinline__ void acc2(float2& a, unsigned int d) {
  a.x += __uint_as_float(d << 16);
  a.y += __uint_as_float(d & 0xffff0000u);
}

// Identifier kernel, zero-parameter form (load-bearing: parameterized variant
// broke the harness in rounds 1-5).
__global__ void UnifiedGNN_56521769616171_kernel() {}

// ---------------- setup ----------------
// Fixed-capacity bucket "CSR": row d owns csr[d*CAP .. d*CAP+63]. One atomic
// pass (gnn_fill) produces BOTH the degree (cnt) and slot positions.
// Buckets are NOT prefilled: aggregation clamps the INDEX per batch
// (v_cndmask: slot >= cnt -> zero-row N) -- branch-free, exact +0.0 dummies.
// dis never materialized: consumers compute rsqrtf(cnt[row]+1) on the fly.

// zero cnt; zero the gather zero-rows of A and A2; build transposed+swizzled
// bf16 copies of W1/W2 in global (Wt layout: us8 chunk index c*16+(kb^(c&15)))
// so GEMM staging is a linear 32 KB copy.
__global__ void gnn_zero(int* cnt, int n, bf16_t* Azrow, bf16_t* A2zrow,
                         const float* W1, const float* W2,
                         bf16_t* Wt1g, bf16_t* Wt2g) {
  int gid = blockIdx.x * 256 + threadIdx.x;
  if (blockIdx.x == 0 && threadIdx.x < 64) {
    ((unsigned int*)Azrow)[threadIdx.x] = 0u;
    ((unsigned int*)A2zrow)[threadIdx.x] = 0u;
  }
  if (gid < 4096) {
    const float* W = (gid < 2048) ? W1 : W2;
    bf16_t* dst = (gid < 2048) ? Wt1g : Wt2g;
    int j = gid & 2047;
    int c = j & 127;
    int kb = j >> 7;  // 0..15
    int k0 = kb << 3;
    us8 v;
#pragma unroll
    for (int q = 0; q < 8; q++) v[q] = f2bf(W[(size_t)(k0 + q) * 128 + c]);
    ((us8*)dst)[c * 16 + (kb ^ (c & 15))] = v;
  }
  if (gid < n) cnt[gid] = 0;
}

// single atomic pass: degree count AND slot placement. R6 form (plain store,
// 1 edge/thread, 43.7us measured). R7's nontemporal+2/thread REGRESSED to
// 54us with identical WRITE_SIZE -- fill is latency/atomic-chain bound, not
// allocate-bound; thread count is the parallelism lever.
__global__ void gnn_fill(const int* src, const int* dst, int* cnt,
                         int* csr, int e, int n) {
  int i = blockIdx.x * 256 + threadIdx.x;
  if (i < e) {
    int d = dst[i];
    if (d >= 0 && d < n) {
      int pos = atomicAdd(&cnt[d], 1);
      if (pos < CAP) csr[(size_t)d * CAP + pos] = src[i];  // guard: mem-safe
    }
  }
}

// ------- MFMA GEMM (conv1): A[r][c] = dis[r]*sum_k X[r][k]*W[k][c] -> bf16 --
// Wg PRE-TRANSPOSED+SWIZZLED bf16; staging = linear 32 KB copy. 512 threads =
// 8 waves x 16 rows = 128 rows/block. Swizzle: 16B chunk kb ^= c&15 ->
// ds_read_b128 bank-uniform. C/D layout (m89): col=lane&15, row=(lane>>4)*4+reg.
// xfmt=0: X f32, in-register hi/lo split (2 MFMAs/k-step, f32-fidelity X).
// xfmt=1: X bf16. s_nop 2 covers VALU->MFMA SrcC hazard; epilogue s_nop 7
// pair operand-tied so acc reads can't hoist.
__global__ __launch_bounds__(512) void gnn_gemm(const void* Xv,
    const bf16_t* Wg, const int* cnt, bf16_t* A, int n, int xfmt) {
  __shared__ __align__(16) bf16_t Wt[128 * 128];  // 32 KB
  int tid = threadIdx.x;

  for (int j = tid; j < 2048; j += 512)
    ((us8*)Wt)[j] = ((const us8*)Wg)[j];
  __syncthreads();

  int lane = tid & 63;
  int wid = tid >> 6;   // 0..7
  int l15 = lane & 15;
  int lk = lane >> 4;   // 0..3
  const bf16_t* Xb = (const bf16_t*)Xv;
  const float* Xf = (const float*)Xv;

  int rowbase = blockIdx.x * 128 + wid * 16;
  int arow = rowbase + l15;
  int arc = arow < n ? arow : (n - 1);

  f32x4 acc[8];
#pragma unroll
  for (int c = 0; c < 8; c++) {
    acc[c][0] = 0.0f; acc[c][1] = 0.0f; acc[c][2] = 0.0f; acc[c][3] = 0.0f;
  }

#pragma unroll
  for (int ks = 0; ks < 4; ks++) {
    int kb = ks * 4 + lk;
    us8 ah, al;
    if (xfmt == 0) {
      float4 a0 = *(const float4*)(Xf + (size_t)arc * 128 + kb * 8);
      float4 a1 = *(const float4*)(Xf + (size_t)arc * 128 + kb * 8 + 4);
      ah[0] = f2bf(a0.x); al[0] = f2bf(a0.x - bf2f(ah[0]));
      ah[1] = f2bf(a0.y); al[1] = f2bf(a0.y - bf2f(ah[1]));
      ah[2] = f2bf(a0.z); al[2] = f2bf(a0.z - bf2f(ah[2]));
      ah[3] = f2bf(a0.w); al[3] = f2bf(a0.w - bf2f(ah[3]));
      ah[4] = f2bf(a1.x); al[4] = f2bf(a1.x - bf2f(ah[4]));
      ah[5] = f2bf(a1.y); al[5] = f2bf(a1.y - bf2f(ah[5]));
      ah[6] = f2bf(a1.z); al[6] = f2bf(a1.z - bf2f(ah[6]));
      ah[7] = f2bf(a1.w); al[7] = f2bf(a1.w - bf2f(ah[7]));
    } else {
      ah = *(const us8*)(Xb + (size_t)arc * 128 + kb * 8);
    }
#pragma unroll
    for (int c = 0; c < 8; c++) {
      int col = c * 16 + l15;
      us8 bf = *(const us8*)&Wt[col * 128 + ((kb ^ l15) << 3)];
      asm volatile("s_nop 2\n\tv_mfma_f32_16x16x32_bf16 %0, %1, %2, %0"
                   : "+v"(acc[c]) : "v"(ah), "v"(bf));
    }
    if (xfmt == 0) {
#pragma unroll
      for (int c = 0; c < 8; c++) {
        int col = c * 16 + l15;
        us8 bf = *(const us8*)&Wt[col * 128 + ((kb ^ l15) << 3)];
        asm volatile("s_nop 2\n\tv_mfma_f32_16x16x32_bf16 %0, %1, %2, %0"
                     : "+v"(acc[c]) : "v"(al), "v"(bf));
      }
    }
  }
  asm volatile("s_nop 7\n\ts_nop 7"
               : "+v"(acc[0]), "+v"(acc[1]), "+v"(acc[2]), "+v"(acc[3]),
                 "+v"(acc[4]), "+v"(acc[5]), "+v"(acc[6]), "+v"(acc[7]));

#pragma unroll
  for (int j = 0; j < 4; j++) {
    int row = rowbase + lk * 4 + j;
    if (row < n) {
      float dd = rsqrtf((float)cnt[row] + 1.0f);
#pragma unroll
      for (int c = 0; c < 8; c++) {
        A[(size_t)row * 128 + c * 16 + l15] = f2bf(acc[c][j] * dd);
      }
    }
  }
}

// ---- FUSED agg+LN+relu -> LDS B-tile -> MFMA gemm (next conv) ----
// GCN dataflow is per-row: agg+LN of row r and the next conv's X@W for row r
// need only row r. Block = 512 thr handles 128 rows: phase A aggregates its
// rows (identical math to gnn_aggln do_ln=1) writing bf16 B ONLY to LDS
// (XOR-swizzled chunks, same scheme as W); __syncthreads; phase B = MFMA gemm
// from LDS B-tile x staged W -> scaled bf16 Aout. Removes 2 launches + B's
// global round-trip. Ain gather + Aout write are different buffers (ping-pong)
// so no cross-block race.
__global__ __launch_bounds__(512) void gnn_agg_gemm(const bf16_t* Ain,
    const int* cnt, const int* csr, const float* bias, const float* ori,
    const float* lnw, const float* lnb, const bf16_t* Wg,
    bf16_t* Aout, int n) {
  __shared__ __align__(16) bf16_t Wt[128 * 128];  // 32 KB
  __shared__ __align__(16) bf16_t Bs[128 * 128];  // 32 KB
  int tid = threadIdx.x;
  int lane = tid & 63;
  int wid = tid >> 6;   // 0..7
  int g = lane >> 4;    // group 0..3
  int l16 = lane & 15;

  // stage W (no dependency on agg phase; covered by the phase barrier)
  for (int j = tid; j < 2048; j += 512)
    ((us8*)Wt)[j] = ((const us8*)Wg)[j];

  const uint4* Av4 = (const uint4*)Ain;

  // ---- phase A: aggregate + LN + relu for 16 rows/wave (4 per group) ----
  for (int rr = 0; rr < 4; rr++) {
    int rt = wid * 16 + rr * 4 + g;        // row within tile 0..127
    int row = blockIdx.x * 128 + rt;
    int rc = row < n ? row : (n - 1);
    int c = cnt[rc];
    int pc = (c + 15) & ~15;
    if (pc > CAP) pc = CAP;
    const int* crow = csr + (size_t)rc * CAP;

    float2 ac[4];
#pragma unroll
    for (int i = 0; i < 4; i++) ac[i] = make_float2(0.0f, 0.0f);

    for (int e = 0; e < pc; e += 16) {
      int raw = crow[e + l16];
      int sv = (e + l16 < c) ? raw : n;  // dummy -> zero row N
#pragma unroll
      for (int half = 0; half < 2; half++) {
        uint4 va[8];
#pragma unroll
        for (int j = 0; j < 8; j++) {
          int s = __shfl(sv, (g << 4) + half * 8 + j);
          va[j] = Av4[(size_t)s * 16 + l16];
        }
#pragma unroll
        for (int j = 0; j < 8; j++) {
          acc2(ac[0], va[j].x);
          acc2(ac[1], va[j].y);
          acc2(ac[2], va[j].z);
          acc2(ac[3], va[j].w);
        }
      }
    }
    {  // self-loop term
      uint4 sv4 = Av4[(size_t)rc * 16 + l16];
      acc2(ac[0], sv4.x);
      acc2(ac[1], sv4.y);
      acc2(ac[2], sv4.z);
      acc2(ac[3], sv4.w);
    }

    float dd = rsqrtf((float)c + 1.0f);
    float4 bb0 = *(const float4*)(bias + l16 * 8);
    float4 bb1 = *(const float4*)(bias + l16 * 8 + 4);
    float4 o0 = *(const float4*)(ori + (size_t)rc * 128 + l16 * 8);
    float4 o1 = *(const float4*)(ori + (size_t)rc * 128 + l16 * 8 + 4);
    float v[8];
    v[0] = dd * ac[0].x + bb0.x + o0.x; v[1] = dd * ac[0].y + bb0.y + o0.y;
    v[2] = dd * ac[1].x + bb0.z + o0.z; v[3] = dd * ac[1].y + bb0.w + o0.w;
    v[4] = dd * ac[2].x + bb1.x + o1.x; v[5] = dd * ac[2].y + bb1.y + o1.y;
    v[6] = dd * ac[3].x + bb1.z + o1.z; v[7] = dd * ac[3].y + bb1.w + o1.w;
    float s = 0.0f, sq = 0.0f;
#pragma unroll
    for (int i = 0; i < 8; i++) { s += v[i]; sq += v[i] * v[i]; }
    for (int off = 8; off >= 1; off >>= 1) {
      s += __shfl_xor(s, off);
      sq += __shfl_xor(sq, off);
    }
    float mu = s * (1.0f / 128.0f);
    float var = sq * (1.0f / 128.0f) - mu * mu;
    float inv = rsqrtf(var + 1e-5f);
    float4 w0 = *(const float4*)(lnw + l16 * 8);
    float4 w1 = *(const float4*)(lnw + l16 * 8 + 4);
    float4 c0 = *(const float4*)(lnb + l16 * 8);
    float4 c1 = *(const float4*)(lnb + l16 * 8 + 4);
    float wv[8] = {w0.x, w0.y, w0.z, w0.w, w1.x, w1.y, w1.z, w1.w};
    float cv[8] = {c0.x, c0.y, c0.z, c0.w, c1.x, c1.y, c1.z, c1.w};
    us8 o8;
#pragma unroll
    for (int i = 0; i < 8; i++) {
      float y = (v[i] - mu) * inv * wv[i] + cv[i];
      if (y < 0.0f) y = 0.0f;
      o8[i] = f2bf(y);
    }
    // LDS store, chunk-swizzled (slot = l16 ^ (rt&15)) -- matches gemm read
    *(us8*)&Bs[rt * 128 + ((l16 ^ (rt & 15)) << 3)] = o8;
  }

  __syncthreads();  // Bs + Wt ready

  // ---- phase B: MFMA gemm from LDS B-tile ----
  int l15 = lane & 15;
  int lk = lane >> 4;
  int rowbase = blockIdx.x * 128 + wid * 16;
  int rt0 = wid * 16 + l15;  // LDS row this lane reads (rt0 & 15 == l15)

  f32x4 acc[8];
#pragma unroll
  for (int c = 0; c < 8; c++) {
    acc[c][0] = 0.0f; acc[c][1] = 0.0f; acc[c][2] = 0.0f; acc[c][3] = 0.0f;
  }

#pragma unroll
  for (int ks = 0; ks < 4; ks++) {
    int kb = ks * 4 + lk;
    us8 ah = *(const us8*)&Bs[rt0 * 128 + ((kb ^ l15) << 3)];
#pragma unroll
    for (int c = 0; c < 8; c++) {
      int col = c * 16 + l15;
      us8 bf = *(const us8*)&Wt[col * 128 + ((kb ^ l15) << 3)];
      asm volatile("s_nop 2\n\tv_mfma_f32_16x16x32_bf16 %0, %1, %2, %0"
                   : "+v"(acc[c]) : "v"(ah), "v"(bf));
    }
  }
  asm volatile("s_nop 7\n\ts_nop 7"
               : "+v"(acc[0]), "+v"(acc[1]), "+v"(acc[2]), "+v"(acc[3]),
                 "+v"(acc[4]), "+v"(acc[5]), "+v"(acc[6]), "+v"(acc[7]));

#pragma unroll
  for (int j = 0; j < 4; j++) {
    int row = rowbase + lk * 4 + j;
    if (row < n) {
      float dd = rsqrtf((float)cnt[row] + 1.0f);
#pragma unroll
      for (int c = 0; c < 8; c++) {
        Aout[(size_t)row * 128 + c * 16 + l15] = f2bf(acc[c][j] * dd);
      }
    }
  }
}

// --- final aggregation (no LN): h_agg -> f32 output ---
// Identical math/structure to prior rounds (frozen: R2/R3/R4 triple-null at
// the L2/L3 random-gather ceiling).
__global__ void gnn_aggln(const bf16_t* A,
    const int* cnt, const int* csr, const float* bias,
    float* Fout, int n) {
  int wid = threadIdx.x >> 6;
  int lane = threadIdx.x & 63;
  int g = lane >> 4;
  int l16 = lane & 15;
  int row = blockIdx.x * 16 + wid * 4 + g;
  bool active = row < n;
  int rc = active ? row : (n - 1);
  int c = cnt[rc];
  int pc = (c + 15) & ~15;
  if (pc > CAP) pc = CAP;
  const int* crow = csr + (size_t)rc * CAP;
  const uint4* Av4 = (const uint4*)A;

  float2 ac[4];
#pragma unroll
  for (int i = 0; i < 4; i++) ac[i] = make_float2(0.0f, 0.0f);

  for (int e = 0; e < pc; e += 16) {
    int raw = crow[e + l16];
    int sv = (e + l16 < c) ? raw : n;
#pragma unroll
    for (int half = 0; half < 2; half++) {
      uint4 va[8];
#pragma unroll
      for (int j = 0; j < 8; j++) {
        int s = __shfl(sv, (g << 4) + half * 8 + j);
        va[j] = Av4[(size_t)s * 16 + l16];
      }
#pragma unroll
      for (int j = 0; j < 8; j++) {
        acc2(ac[0], va[j].x);
        acc2(ac[1], va[j].y);
        acc2(ac[2], va[j].z);
        acc2(ac[3], va[j].w);
      }
    }
  }
  {
    uint4 sv4 = Av4[(size_t)rc * 16 + l16];
    acc2(ac[0], sv4.x);
    acc2(ac[1], sv4.y);
    acc2(ac[2], sv4.z);
    acc2(ac[3], sv4.w);
  }

  float dd = rsqrtf((float)c + 1.0f);
  float4 bb0 = *(const float4*)(bias + l16 * 8);
  float4 bb1 = *(const float4*)(bias + l16 * 8 + 4);
  if (active) {
    float4 f0 = make_float4(dd * ac[0].x + bb0.x, dd * ac[0].y + bb0.y,
                            dd * ac[1].x + bb0.z, dd * ac[1].y + bb0.w);
    float4 f1 = make_float4(dd * ac[2].x + bb1.x, dd * ac[2].y + bb1.y,
                            dd * ac[3].x + bb1.z, dd * ac[3].y + bb1.w);
    *(float4*)(Fout + (size_t)rc * 128 + l16 * 8) = f0;
    *(float4*)(Fout + (size_t)rc * 128 + l16 * 8 + 4) = f1;
  }
}

// ---------------- driver ----------------

extern "C" void kernel_launch(void* const* d_in, const int* in_sizes, int n_in,
                              void* d_out, int out_size, void* d_ws, size_t ws_size,
                              hipStream_t stream) {
  UnifiedGNN_56521769616171_kernel<<<1, 64, 0, stream>>>();

  // input classification by size (identity under documented dict order)
  int nI = (n_in > 0 && n_in <= 16) ? n_in : 11;
  long best = -1;
  int iFeat = 0;
  for (int i = 0; i < nI; i++)
    if ((long)in_sizes[i] > best) { best = in_sizes[i]; iFeat = i; }
  int iW[2], iV[6], iE[2];
  int nW = 0, nV = 0, nE = 0;
  for (int i = 0; i < nI; i++) {
    if (i == iFeat) continue;
    int s = in_sizes[i];
    if (s == 128 * 128) { if (nW < 2) iW[nW++] = i; }
    else if (s == 128)  { if (nV < 6) iV[nV++] = i; }
    else                { if (nE < 2) iE[nE++] = i; }
  }
  int aFeat = 0, aEs = 1, aEd = 2, aW1 = 3, aB1 = 4, aW2 = 5, aB2 = 6,
      aL1w = 7, aL1b = 8, aL2w = 9, aL2b = 10;
  if (nW == 2 && nV == 6 && nE == 2) {
    aFeat = iFeat;
    aEs = iE[0]; aEd = iE[1];
    aW1 = iW[0]; aW2 = iW[1];
    aB1 = iV[0]; aB2 = iV[1];
    aL1w = iV[2]; aL1b = iV[3]; aL2w = iV[4]; aL2b = iV[5];
  }

  int N = 50000;
  int E = 600000;
  if (in_sizes[aFeat] > 0 && (in_sizes[aFeat] % 128) == 0) N = in_sizes[aFeat] / 128;
  if (in_sizes[aEs] > 0) E = in_sizes[aEs];

  const float* in_feat = (const float*)d_in[aFeat];
  const int*   esrc    = (const int*)d_in[aEs];
  const int*   edst    = (const int*)d_in[aEd];
  const float* W1      = (const float*)d_in[aW1];
  const float* b1      = (const float*)d_in[aB1];
  const float* W2      = (const float*)d_in[aW2];
  const float* b2      = (const float*)d_in[aB2];
  const float* ln1w    = (const float*)d_in[aL1w];
  const float* ln1b    = (const float*)d_in[aL1b];
  const float* ln2w    = (const float*)d_in[aL2w];
  const float* ln2b    = (const float*)d_in[aL2b];

  // workspace carve (~52 MB; ws_size = 256 MiB)
  char* base = (char*)d_ws;
  size_t off = 0;
  int* cnt = (int*)(base + off);      off += ((size_t)N * 4 + 255) & ~(size_t)255;
  int* csr = (int*)(base + off);      off += ((size_t)N * CAP * 4 + 255) & ~(size_t)255;
  bf16_t* A = (bf16_t*)(base + off);  off += ((size_t)(N + 1) * 256 + 255) & ~(size_t)255;   // +1 zero row
  bf16_t* A2 = (bf16_t*)(base + off); off += ((size_t)(N + 1) * 256 + 255) & ~(size_t)255;   // ping-pong
  bf16_t* Wt1g = (bf16_t*)(base + off); off += 32768;  // pre-swizzled bf16 W1
  bf16_t* Wt2g = (bf16_t*)(base + off); off += 32768;  // pre-swizzled bf16 W2

  int gZ = (N + 255) / 256;   // covers cnt zero + W convert (N >= 4096)
  int gE = (E + 255) / 256;
  int nt128 = (N + 127) / 128;
  int agg_grid = (N + 15) / 16;

  gnn_zero<<<gZ, 256, 0, stream>>>(cnt, N, A + (size_t)N * 128,
                                   A2 + (size_t)N * 128, W1, W2, Wt1g, Wt2g);
  gnn_fill<<<gE, 256, 0, stream>>>(esrc, edst, cnt, csr, E, N);

  // conv1: A = dis*(in_feat@W1)  (f32 X, in-register hi/lo split)
  gnn_gemm<<<nt128, 512, 0, stream>>>(in_feat, Wt1g, cnt, A, N, 0);

  // fused: agg1+LN1+relu (B in LDS) -> gemm2 -> A2
  gnn_agg_gemm<<<nt128, 512, 0, stream>>>(A, cnt, csr, b1, in_feat,
                                          ln1w, ln1b, Wt2g, A2, N);

  // fused: agg2+LN2+relu (B in LDS) -> gemm3 -> A
  gnn_agg_gemm<<<nt128, 512, 0, stream>>>(A2, cnt, csr, b2, in_feat,
                                          ln2w, ln2b, Wt2g, A, N);

  // final aggregation -> f32 output
  gnn_aggln<<<agg_grid, 256, 0, stream>>>(A, cnt, csr, b2, (float*)d_out, N);
}